// Round 1
// 403.136 us; speedup vs baseline: 1.0390x; 1.0390x over previous
//
#include <hip/hip_runtime.h>

// Problem constants (fixed by setup_inputs):
//   B=16, L=4096 (64x64 grid), H=1152, output_length=1024 -> k=2, k^2=4
#define BB 16
#define LL 4096
#define HH 1152
#define OUT_LEN 1024
#define KK 2
#define CAP 8              // inverse-list capacity per segment (data gives exactly 4)
#define H4 (HH / 4)        // 288 float4 per row
#define H8 (HH / 8)        // 144: each thread handles vf4 chunks h8 and h8+144
#define GRID_W 64

typedef float vf4 __attribute__((ext_vector_type(4)));

// ---------------- Kernel A: per-batch prep ----------------
// zero cnt, compute maxx = max(clamp(pos_x,0))+1, and validate the canonical
// fast path: pos == (i%64, i/64) for all i and no padding  ->  flag[b]=1
__global__ __launch_bounds__(1024) void prep_kernel(const int* __restrict__ pos,
                                                    const int* __restrict__ pad,
                                                    int* __restrict__ maxx,
                                                    int* __restrict__ flag,
                                                    int* __restrict__ cnt) {
    const int b = blockIdx.x;
    const int tid = threadIdx.x;
    cnt[b * OUT_LEN + tid] = 0;                    // 1024 counters, 1024 threads

    int m = 0;
    int canon = 1;
    const int2* __restrict__ pp = (const int2*)pos;
    #pragma unroll
    for (int j = 0; j < LL / 1024; ++j) {
        const int i = j * 1024 + tid;
        const int2 q = pp[(size_t)b * LL + i];
        m = max(m, max(q.x, 0));
        canon &= (q.x == (i & (GRID_W - 1))) & (q.y == (i >> 6)) & (pad[b * LL + i] == 0);
    }
    __shared__ int sm[1024];
    __shared__ int sc[1024];
    sm[tid] = m; sc[tid] = canon;
    __syncthreads();
    for (int s = 512; s > 0; s >>= 1) {
        if (tid < s) { sm[tid] = max(sm[tid], sm[tid + s]); sc[tid] &= sc[tid + s]; }
        __syncthreads();
    }
    if (tid == 0) {
        maxx[b] = sm[0] + 1;
        flag[b] = sc[0] & ((sm[0] + 1) == GRID_W);  // closed form needs segw==32
    }
}

// ---------------- Kernel B: build inverse lists (fallback path only) ----------
__global__ void build_inv(const int* __restrict__ pos, const int* __restrict__ pad,
                          const int* __restrict__ maxx, const int* __restrict__ flag,
                          int* __restrict__ cnt, int* __restrict__ inv) {
    const int fl = blockIdx.x * 256 + threadIdx.x;   // fl = b*LL + i
    const int b = fl >> 12;           // / LL
    if (flag[b]) return;              // canonical batch: inverse lists unneeded
    const int i = fl & (LL - 1);      // % LL
    int x = max(pos[2 * (size_t)fl], 0);
    int y = max(pos[2 * (size_t)fl + 1], 0);
    const int segw = maxx[b] / KK;
    const int seg = x / KK + segw * (y / KK);
    const int base = b * OUT_LEN + seg;
    const int slot = atomicAdd(&cnt[base], 1);
    if (slot < CAP) inv[base * CAP + slot] = pad[fl] ? (i | 0x80000000) : i;
}

// ---------------- Kernel C: gather + mean(k^2) + scale, plus mask ------------
// Layout change vs previous version: thread owns vf4 chunks (h8, h8+144) so each
// load/store instruction is a contiguous 1KB per wave (full-line utilization).
__global__ __launch_bounds__(256) void gather_pool(
    const float* __restrict__ hs, const int* __restrict__ cnt, const int* __restrict__ inv,
    const int* __restrict__ flag, float* __restrict__ out) {
    const int id = blockIdx.x * 256 + threadIdx.x;   // [0, BB*OUT_LEN*H8)
    const int h8 = id % H8;                           // which 16B chunk pair of the row
    const int t  = id / H8;                           // t = b*OUT_LEN + s
    const int b  = t >> 10;                           // / OUT_LEN

    const vf4* __restrict__ hp = (const vf4*)hs;
    vf4 a0 = (vf4)0.0f;
    vf4 a1 = (vf4)0.0f;
    float maskv = 1.0f;

    if (flag[b]) {
        // canonical grid: segment s=(sx,sy) pools rows {i0, i0+1, i0+64, i0+65}
        const int s  = t & (OUT_LEN - 1);
        const int sx = s & 31;
        const int sy = s >> 5;
        const int i0 = (sx << 1) + (sy << 7);         // 2*sx + 128*sy
        const vf4* p = hp + (size_t)(b * LL + i0) * H4 + h8;
        // 8 independent address-computed loads -> full MLP, zero index traffic
        vf4 r0 = __builtin_nontemporal_load(p);
        vf4 r1 = __builtin_nontemporal_load(p + H4);
        vf4 r2 = __builtin_nontemporal_load(p + 64 * H4);
        vf4 r3 = __builtin_nontemporal_load(p + 65 * H4);
        vf4 r4 = __builtin_nontemporal_load(p + H8);
        vf4 r5 = __builtin_nontemporal_load(p + H4 + H8);
        vf4 r6 = __builtin_nontemporal_load(p + 64 * H4 + H8);
        vf4 r7 = __builtin_nontemporal_load(p + 65 * H4 + H8);
        a0 = (r0 + r1) + (r2 + r3);
        a1 = (r4 + r5) + (r6 + r7);
    } else {
        const int c  = cnt[t];
        const int cc = min(c, CAP);
        #pragma unroll 4
        for (int j = 0; j < cc; ++j) {
            const int ii = inv[t * CAP + j];
            if (ii >= 0) {                            // padded patches contribute 0
                const vf4* p = hp + (size_t)(b * LL + ii) * H4 + h8;
                a0 += __builtin_nontemporal_load(p);
                a1 += __builtin_nontemporal_load(p + H8);
            }
        }
        maskv = (c > 0) ? 1.0f : 0.0f;
    }

    // pooled = sum / k^2; then * sqrt(H):  sqrt(1152)/4
    const float scale = 8.485281374238571f;
    a0 *= scale;
    a1 *= scale;

    vf4* op = (vf4*)out + (size_t)t * H4 + h8;
    __builtin_nontemporal_store(a0, op);
    __builtin_nontemporal_store(a1, op + H8);

    // mask output: counts > 0 (canonical path: every segment has 4 sources)
    if (h8 == 0) out[(size_t)BB * OUT_LEN * HH + t] = maskv;
}

extern "C" void kernel_launch(void* const* d_in, const int* in_sizes, int n_in,
                              void* d_out, int out_size, void* d_ws, size_t ws_size,
                              hipStream_t stream) {
    const float* hs  = (const float*)d_in[0];   // [B, L, H] fp32
    const int*   pos = (const int*)d_in[1];     // [B, L, 2] int
    const int*   pad = (const int*)d_in[2];     // [B, L] bool->int
    float* out = (float*)d_out;                 // [B,1024,1152] fp32 ++ [B,1024] mask

    int* ws   = (int*)d_ws;
    int* maxx = ws;                             // BB ints (64-padded)
    int* flag = ws + 64;                        // BB ints (64-padded)
    int* cnt  = ws + 128;                       // BB*OUT_LEN ints
    int* inv  = cnt + BB * OUT_LEN;             // BB*OUT_LEN*CAP ints

    prep_kernel<<<BB, 1024, 0, stream>>>(pos, pad, maxx, flag, cnt);
    build_inv<<<(BB * LL) / 256, 256, 0, stream>>>(pos, pad, maxx, flag, cnt, inv);
    gather_pool<<<(BB * OUT_LEN * H8) / 256, 256, 0, stream>>>(hs, cnt, inv, flag, out);
}

// Round 2
// 402.949 us; speedup vs baseline: 1.0394x; 1.0005x over previous
//
#include <hip/hip_runtime.h>

// Problem constants (fixed by setup_inputs):
//   B=16, L=4096 (64x64 grid), H=1152, output_length=1024 -> k=2, k^2=4
#define BB 16
#define LL 4096
#define HH 1152
#define OUT_LEN 1024
#define KK 2
#define CAP 8              // inverse-list capacity per segment (data gives exactly 4)
#define H4 (HH / 4)        // 288 float4 per row
#define H8 (HH / 8)        // 144: each thread handles vf4 chunks h8 and h8+144
#define GRID_W 64

typedef float vf4 __attribute__((ext_vector_type(4)));

// ---------------- Kernel 1: fused per-batch prep + fallback inverse-list build --
// One block per batch. Zero cnt, compute maxx/canonical flag via wave reduction,
// write the canonical mask row, and (only if non-canonical) build the inverse
// lists reusing the pos/pad values already in registers.
__global__ __launch_bounds__(1024) void prep_build(const int* __restrict__ pos,
                                                   const int* __restrict__ pad,
                                                   int* __restrict__ flag,
                                                   int* __restrict__ cnt,
                                                   int* __restrict__ inv,
                                                   float* __restrict__ out_mask) {
    const int b = blockIdx.x;
    const int tid = threadIdx.x;
    int* __restrict__ bcnt = cnt + b * OUT_LEN;
    bcnt[tid] = 0;                                   // 1024 counters, 1024 threads

    int m = 0, canon = 1;
    int xs[4], ys[4], ps[4];
    const int2* __restrict__ pp = (const int2*)pos + (size_t)b * LL;
    #pragma unroll
    for (int j = 0; j < 4; ++j) {
        const int i = j * 1024 + tid;
        const int2 q = pp[i];
        ps[j] = pad[b * LL + i];
        xs[j] = max(q.x, 0);
        ys[j] = max(q.y, 0);
        m = max(m, xs[j]);
        canon &= (q.x == (i & (GRID_W - 1))) & (q.y == (i >> 6)) & (ps[j] == 0);
    }
    // wave-level reduction (64 lanes), then 16 wave results via LDS
    #pragma unroll
    for (int off = 32; off > 0; off >>= 1) {
        m = max(m, __shfl_down(m, off));
        canon &= __shfl_down(canon, off);
    }
    __shared__ int sm[16], sc[16];
    __shared__ int s_maxx, s_flag;
    const int wave = tid >> 6, lane = tid & 63;
    if (lane == 0) { sm[wave] = m; sc[wave] = canon; }
    __syncthreads();
    if (tid == 0) {
        int mm = 0, cc = 1;
        #pragma unroll
        for (int w = 0; w < 16; ++w) { mm = max(mm, sm[w]); cc &= sc[w]; }
        s_maxx = mm + 1;
        s_flag = cc & ((mm + 1) == GRID_W);          // closed form needs segw==32
        flag[b] = s_flag;
    }
    __syncthreads();
    if (s_flag) {
        // canonical: every segment has 4 sources -> mask row is all ones
        out_mask[b * OUT_LEN + tid] = 1.0f;
        return;
    }
    // fallback: build inverse lists for this batch (pos/pad already in registers)
    const int segw = s_maxx / KK;
    #pragma unroll
    for (int j = 0; j < 4; ++j) {
        const int i = j * 1024 + tid;
        const int seg = xs[j] / KK + segw * (ys[j] / KK);
        const int slot = atomicAdd(&bcnt[seg], 1);
        if (slot < CAP) inv[(b * OUT_LEN + seg) * CAP + slot] = ps[j] ? (i | 0x80000000) : i;
    }
}

// ---------------- Kernel 2: gather + mean(k^2) + scale ------------------------
// Thread owns vf4 chunks (h8, h8+144) of one output row: every load/store
// instruction is a contiguous 1KB per wave (full-line utilization).
__global__ __launch_bounds__(256) void gather_pool(
    const float* __restrict__ hs, const int* __restrict__ cnt, const int* __restrict__ inv,
    const int* __restrict__ flag, float* __restrict__ out) {
    const int id = blockIdx.x * 256 + threadIdx.x;   // [0, BB*OUT_LEN*H8)
    const int h8 = id % H8;                           // which 16B chunk pair of the row
    const int t  = id / H8;                           // t = b*OUT_LEN + s
    const int b  = t >> 10;                           // / OUT_LEN

    const vf4* __restrict__ hp = (const vf4*)hs;
    vf4 a0 = (vf4)0.0f;
    vf4 a1 = (vf4)0.0f;
    const int flagv = flag[b];

    if (flagv) {
        // canonical grid: segment s=(sx,sy) pools rows {i0, i0+1, i0+64, i0+65}
        const int s  = t & (OUT_LEN - 1);
        const int sx = s & 31;
        const int sy = s >> 5;
        const int i0 = (sx << 1) + (sy << 7);         // 2*sx + 128*sy
        const vf4* p = hp + (size_t)(b * LL + i0) * H4 + h8;
        // 8 independent address-computed loads -> full MLP, zero index traffic
        vf4 r0 = __builtin_nontemporal_load(p);
        vf4 r1 = __builtin_nontemporal_load(p + H4);
        vf4 r2 = __builtin_nontemporal_load(p + 64 * H4);
        vf4 r3 = __builtin_nontemporal_load(p + 65 * H4);
        vf4 r4 = __builtin_nontemporal_load(p + H8);
        vf4 r5 = __builtin_nontemporal_load(p + H4 + H8);
        vf4 r6 = __builtin_nontemporal_load(p + 64 * H4 + H8);
        vf4 r7 = __builtin_nontemporal_load(p + 65 * H4 + H8);
        a0 = (r0 + r1) + (r2 + r3);
        a1 = (r4 + r5) + (r6 + r7);
    } else {
        const int c  = cnt[t];
        const int cc = min(c, CAP);
        #pragma unroll 4
        for (int j = 0; j < cc; ++j) {
            const int ii = inv[t * CAP + j];
            if (ii >= 0) {                            // padded patches contribute 0
                const vf4* p = hp + (size_t)(b * LL + ii) * H4 + h8;
                a0 += __builtin_nontemporal_load(p);
                a1 += __builtin_nontemporal_load(p + H8);
            }
        }
        // mask output for non-canonical batches: counts > 0
        if (h8 == 0) out[(size_t)BB * OUT_LEN * HH + t] = (c > 0) ? 1.0f : 0.0f;
    }

    // pooled = sum / k^2; then * sqrt(H):  sqrt(1152)/4
    const float scale = 8.485281374238571f;
    a0 *= scale;
    a1 *= scale;

    vf4* op = (vf4*)out + (size_t)t * H4 + h8;
    __builtin_nontemporal_store(a0, op);
    __builtin_nontemporal_store(a1, op + H8);
}

extern "C" void kernel_launch(void* const* d_in, const int* in_sizes, int n_in,
                              void* d_out, int out_size, void* d_ws, size_t ws_size,
                              hipStream_t stream) {
    const float* hs  = (const float*)d_in[0];   // [B, L, H] fp32
    const int*   pos = (const int*)d_in[1];     // [B, L, 2] int
    const int*   pad = (const int*)d_in[2];     // [B, L] bool->int
    float* out = (float*)d_out;                 // [B,1024,1152] fp32 ++ [B,1024] mask
    float* out_mask = out + (size_t)BB * OUT_LEN * HH;

    int* ws   = (int*)d_ws;
    int* flag = ws;                             // BB ints (64-padded)
    int* cnt  = ws + 64;                        // BB*OUT_LEN ints
    int* inv  = cnt + BB * OUT_LEN;             // BB*OUT_LEN*CAP ints

    prep_build<<<BB, 1024, 0, stream>>>(pos, pad, flag, cnt, inv, out_mask);
    gather_pool<<<(BB * OUT_LEN * H8) / 256, 256, 0, stream>>>(hs, cnt, inv, flag, out);
}

// Round 3
// 401.805 us; speedup vs baseline: 1.0424x; 1.0028x over previous
//
#include <hip/hip_runtime.h>

// Problem constants (fixed by setup_inputs):
//   B=16, L=4096 (64x64 grid), H=1152, output_length=1024 -> k=2, k^2=4
#define BB 16
#define LL 4096
#define HH 1152
#define OUT_LEN 1024
#define KK 2
#define CAP 8              // inverse-list capacity per segment (data gives exactly 4)
#define H4 (HH / 4)        // 288 float4 per row
#define T_SEG 72           // threads per segment; each owns 4 vf4: h72 + {0,72,144,216}
#define GRID_W 64

typedef float vf4 __attribute__((ext_vector_type(4)));

// ---------------- Kernel 1: fused per-batch prep + fallback inverse-list build --
// One block per batch. Zero cnt, compute maxx/canonical flag via wave reduction,
// write the canonical mask row, and (only if non-canonical) build the inverse
// lists reusing the pos/pad values already in registers.
__global__ __launch_bounds__(1024) void prep_build(const int* __restrict__ pos,
                                                   const int* __restrict__ pad,
                                                   int* __restrict__ flag,
                                                   int* __restrict__ cnt,
                                                   int* __restrict__ inv,
                                                   float* __restrict__ out_mask) {
    const int b = blockIdx.x;
    const int tid = threadIdx.x;
    int* __restrict__ bcnt = cnt + b * OUT_LEN;
    bcnt[tid] = 0;                                   // 1024 counters, 1024 threads

    int m = 0, canon = 1;
    int xs[4], ys[4], ps[4];
    const int2* __restrict__ pp = (const int2*)pos + (size_t)b * LL;
    #pragma unroll
    for (int j = 0; j < 4; ++j) {
        const int i = j * 1024 + tid;
        const int2 q = pp[i];
        ps[j] = pad[b * LL + i];
        xs[j] = max(q.x, 0);
        ys[j] = max(q.y, 0);
        m = max(m, xs[j]);
        canon &= (q.x == (i & (GRID_W - 1))) & (q.y == (i >> 6)) & (ps[j] == 0);
    }
    // wave-level reduction (64 lanes), then 16 wave results via LDS
    #pragma unroll
    for (int off = 32; off > 0; off >>= 1) {
        m = max(m, __shfl_down(m, off));
        canon &= __shfl_down(canon, off);
    }
    __shared__ int sm[16], sc[16];
    __shared__ int s_maxx, s_flag;
    const int wave = tid >> 6, lane = tid & 63;
    if (lane == 0) { sm[wave] = m; sc[wave] = canon; }
    __syncthreads();
    if (tid == 0) {
        int mm = 0, cc = 1;
        #pragma unroll
        for (int w = 0; w < 16; ++w) { mm = max(mm, sm[w]); cc &= sc[w]; }
        s_maxx = mm + 1;
        s_flag = cc & ((mm + 1) == GRID_W);          // closed form needs segw==32
        flag[b] = s_flag;
    }
    __syncthreads();
    if (s_flag) {
        // canonical: every segment has 4 sources -> mask row is all ones
        out_mask[b * OUT_LEN + tid] = 1.0f;
        return;
    }
    // fallback: build inverse lists for this batch (pos/pad already in registers)
    const int segw = s_maxx / KK;
    #pragma unroll
    for (int j = 0; j < 4; ++j) {
        const int i = j * 1024 + tid;
        const int seg = xs[j] / KK + segw * (ys[j] / KK);
        const int slot = atomicAdd(&bcnt[seg], 1);
        if (slot < CAP) inv[(b * OUT_LEN + seg) * CAP + slot] = ps[j] ? (i | 0x80000000) : i;
    }
}

// ---------------- Kernel 2: gather + mean(k^2) + scale ------------------------
// 72 threads per output segment; thread owns vf4 chunks h72 + {0,72,144,216}.
// Every load/store instruction remains a contiguous ~1.15KB run per wave; each
// thread keeps 16 independent loads in flight (2x MLP vs previous round).
__global__ __launch_bounds__(256) void gather_pool(
    const float* __restrict__ hs, const int* __restrict__ cnt, const int* __restrict__ inv,
    const int* __restrict__ flag, float* __restrict__ out) {
    const int id = blockIdx.x * 256 + threadIdx.x;   // [0, BB*OUT_LEN*T_SEG)
    const int h72 = id % T_SEG;                       // chunk group within the row
    const int t   = id / T_SEG;                       // t = b*OUT_LEN + s
    const int b   = t >> 10;                          // / OUT_LEN

    const vf4* __restrict__ hp = (const vf4*)hs;
    vf4 a0 = (vf4)0.0f, a1 = (vf4)0.0f, a2 = (vf4)0.0f, a3 = (vf4)0.0f;

    if (flag[b]) {
        // canonical grid: segment s=(sx,sy) pools rows {i0, i0+1, i0+64, i0+65}
        const int s  = t & (OUT_LEN - 1);
        const int sx = s & 31;
        const int sy = s >> 5;
        const int i0 = (sx << 1) + (sy << 7);         // 2*sx + 128*sy
        const vf4* p0 = hp + (size_t)(b * LL + i0) * H4 + h72;
        const vf4* p1 = p0 + H4;
        const vf4* p2 = p0 + 64 * H4;
        const vf4* p3 = p0 + 65 * H4;
        // 16 independent address-computed loads -> full MLP, zero index traffic
        vf4 r00 = __builtin_nontemporal_load(p0);
        vf4 r01 = __builtin_nontemporal_load(p0 + 72);
        vf4 r02 = __builtin_nontemporal_load(p0 + 144);
        vf4 r03 = __builtin_nontemporal_load(p0 + 216);
        vf4 r10 = __builtin_nontemporal_load(p1);
        vf4 r11 = __builtin_nontemporal_load(p1 + 72);
        vf4 r12 = __builtin_nontemporal_load(p1 + 144);
        vf4 r13 = __builtin_nontemporal_load(p1 + 216);
        vf4 r20 = __builtin_nontemporal_load(p2);
        vf4 r21 = __builtin_nontemporal_load(p2 + 72);
        vf4 r22 = __builtin_nontemporal_load(p2 + 144);
        vf4 r23 = __builtin_nontemporal_load(p2 + 216);
        vf4 r30 = __builtin_nontemporal_load(p3);
        vf4 r31 = __builtin_nontemporal_load(p3 + 72);
        vf4 r32 = __builtin_nontemporal_load(p3 + 144);
        vf4 r33 = __builtin_nontemporal_load(p3 + 216);
        a0 = (r00 + r10) + (r20 + r30);
        a1 = (r01 + r11) + (r21 + r31);
        a2 = (r02 + r12) + (r22 + r32);
        a3 = (r03 + r13) + (r23 + r33);
    } else {
        const int c  = cnt[t];
        const int cc = min(c, CAP);
        #pragma unroll 4
        for (int j = 0; j < cc; ++j) {
            const int ii = inv[t * CAP + j];
            if (ii >= 0) {                            // padded patches contribute 0
                const vf4* p = hp + (size_t)(b * LL + ii) * H4 + h72;
                a0 += __builtin_nontemporal_load(p);
                a1 += __builtin_nontemporal_load(p + 72);
                a2 += __builtin_nontemporal_load(p + 144);
                a3 += __builtin_nontemporal_load(p + 216);
            }
        }
        // mask output for non-canonical batches: counts > 0
        if (h72 == 0) out[(size_t)BB * OUT_LEN * HH + t] = (c > 0) ? 1.0f : 0.0f;
    }

    // pooled = sum / k^2; then * sqrt(H):  sqrt(1152)/4
    const float scale = 8.485281374238571f;
    a0 *= scale; a1 *= scale; a2 *= scale; a3 *= scale;

    vf4* op = (vf4*)out + (size_t)t * H4 + h72;
    __builtin_nontemporal_store(a0, op);
    __builtin_nontemporal_store(a1, op + 72);
    __builtin_nontemporal_store(a2, op + 144);
    __builtin_nontemporal_store(a3, op + 216);
}

extern "C" void kernel_launch(void* const* d_in, const int* in_sizes, int n_in,
                              void* d_out, int out_size, void* d_ws, size_t ws_size,
                              hipStream_t stream) {
    const float* hs  = (const float*)d_in[0];   // [B, L, H] fp32
    const int*   pos = (const int*)d_in[1];     // [B, L, 2] int
    const int*   pad = (const int*)d_in[2];     // [B, L] bool->int
    float* out = (float*)d_out;                 // [B,1024,1152] fp32 ++ [B,1024] mask
    float* out_mask = out + (size_t)BB * OUT_LEN * HH;

    int* ws   = (int*)d_ws;
    int* flag = ws;                             // BB ints (64-padded)
    int* cnt  = ws + 64;                        // BB*OUT_LEN ints
    int* inv  = cnt + BB * OUT_LEN;             // BB*OUT_LEN*CAP ints

    prep_build<<<BB, 1024, 0, stream>>>(pos, pad, flag, cnt, inv, out_mask);
    gather_pool<<<(BB * OUT_LEN * T_SEG) / 256, 256, 0, stream>>>(hs, cnt, inv, flag, out);
}